// Round 7
// baseline (5458.912 us; speedup 1.0000x reference)
//
#include <hip/hip_runtime.h>
#include <hip/hip_bf16.h>

// ---------------------------------------------------------------------------
// MySCNN: 3 towers x (conv 4->120, conv 120->120, conv 120->4), K=5, lrelu.
// Round 6->7: conv2 restructured as Horner with the channel-mix GEMM FUSED
// into the CSR SpMM kernel (k_fused): w = Theta_k x + L w. Removes the
// y read-modify-write stream and 24 GEMM dispatches; MACs hide under
// gather latency (csr120 showed VALUBusy 11%).
// conv1 powers / conv3 Horner: thread-per-row float4 CSR (edges read once).
// Layout: channel-last slabs (Mp,120); pad rows [M,Mp) inert.
// ---------------------------------------------------------------------------

#define LRELU(v) ((v) > 0.f ? (v) : 0.01f * (v))

// ---- per-batch transpose x (4,M) -> SP slot k=0: SP[m*20 + i] --------------
__global__ void k_xpose_in(const float* __restrict__ x, float* __restrict__ SP, int M) {
    int idx = blockIdx.x * blockDim.x + threadIdx.x;
    if (idx >= M * 4) return;
    int i = idx / M, m = idx - i * M;
    SP[(size_t)m * 20 + i] = x[idx];
}

// ---- theta transpose: dst[(k*Cin+i)*Cpad + o] = src[(o*Cin+i)*K + k] -------
__global__ void k_xpose_th(const float* __restrict__ src, float* __restrict__ dst,
                           int Cout, int Cin, int K, int Cpad) {
    int idx = blockIdx.x * blockDim.x + threadIdx.x;
    int tot = K * Cin * Cpad;
    if (idx >= tot) return;
    int o = idx % Cpad;
    int rest = idx / Cpad;
    int i = rest % Cin;
    int k = rest / Cin;
    dst[idx] = (o < Cout) ? src[((size_t)o * Cin + i) * K + k] : 0.f;
}

// ============================ CSR build =====================================
__global__ void k_hist(const int* __restrict__ rows, int nnz, int* __restrict__ cnt) {
    int e = blockIdx.x * blockDim.x + threadIdx.x;
    if (e < nnz) atomicAdd(&cnt[rows[e]], 1);
}

__global__ __launch_bounds__(256) void k_scan1(const int* __restrict__ cnt, int M,
                                               int* __restrict__ rp, int* __restrict__ part) {
    __shared__ int lds[256];
    int tid = threadIdx.x;
    int i = blockIdx.x * 256 + tid;
    int v = (i < M) ? cnt[i] : 0;
    lds[tid] = v;
    __syncthreads();
    for (int off = 1; off < 256; off <<= 1) {
        int t = (tid >= off) ? lds[tid - off] : 0;
        __syncthreads();
        lds[tid] += t;
        __syncthreads();
    }
    if (i < M) rp[i] = lds[tid] - v;
    if (tid == 255) part[blockIdx.x] = lds[255];
}

__global__ __launch_bounds__(512) void k_scan2(int* __restrict__ part, int npart) {
    __shared__ int lds[512];
    int tid = threadIdx.x;
    int v = (tid < npart) ? part[tid] : 0;
    lds[tid] = v;
    __syncthreads();
    for (int off = 1; off < 512; off <<= 1) {
        int t = (tid >= off) ? lds[tid - off] : 0;
        __syncthreads();
        lds[tid] += t;
        __syncthreads();
    }
    if (tid < npart) part[tid] = lds[tid] - v;
}

__global__ void k_scan3(int* __restrict__ rp, int* __restrict__ cur,
                        const int* __restrict__ part, int M, int nnz) {
    int i = blockIdx.x * 256 + threadIdx.x;
    if (i < M) {
        int r = rp[i] + part[blockIdx.x];
        rp[i] = r;
        cur[i] = r;
    }
    if (i == 0) rp[M] = nnz;
}

__global__ void k_scatter(const int* __restrict__ rows, const int* __restrict__ cols,
                          const float* __restrict__ vals, int nnz,
                          int* __restrict__ cur, int* __restrict__ col2,
                          float* __restrict__ val2) {
    int e = blockIdx.x * blockDim.x + threadIdx.x;
    if (e >= nnz) return;
    int pos = atomicAdd(&cur[rows[e]], 1);
    col2[pos] = cols[e];
    val2[pos] = vals[e];
}

// ============================ fused Horner step ==============================
// w_new[row] = (FINAL? lrelu(. + bias) : .)( Theta_k x[row] + (L w_old)[row] )
// 1024 threads = 16 waves = 16 rows/block. theta (120,120)[i][o] in LDS.
template <int FINAL>
__global__ __launch_bounds__(1024) void k_fused(
    const int* __restrict__ rp, const int* __restrict__ col2,
    const float* __restrict__ val2,
    const float* __restrict__ w_old,  // gather source (Mp,120)
    const float* __restrict__ x,      // dense operand (Mp,120)
    const float* __restrict__ tht,    // (120,120) [i][o]
    const float* __restrict__ bias,   // 120 (FINAL only)
    float* __restrict__ w_new, int M) {
    __shared__ float th_lds[120 * 120];     // 57600 B
    __shared__ float x_lds[16][120];        // 7680 B   (total 65280 <= 64KB)
    int tid = threadIdx.x;
    {
        const float4* s = (const float4*)tht;
        float4* d = (float4*)th_lds;
        for (int t = tid; t < 3600; t += 1024) d[t] = s[t];
    }
    int wv = tid >> 6, lane = tid & 63;
    int row = blockIdx.x * 16 + wv;
    int c = lane * 2;
    bool act = (c < 120) && (row < M);
    if (act) *(float2*)&x_lds[wv][c] = *(const float2*)&x[(size_t)row * 120 + c];
    float ax = 0.f, ay = 0.f;
    if (row < M) {
        int e0 = rp[row], e1 = rp[row + 1];
        for (int e = e0; e < e1; ++e) {
            float v = val2[e];
            int col = col2[e];
            if (act) {
                float2 xv = *(const float2*)&w_old[(size_t)col * 120 + c];
                ax += v * xv.x;
                ay += v * xv.y;
            }
        }
    }
    __syncthreads();
    if (act) {
        float accx = 0.f, accy = 0.f;
#pragma unroll 4
        for (int i = 0; i < 120; ++i) {
            float t = x_lds[wv][i];
            float2 th = *(const float2*)&th_lds[i * 120 + c];
            accx += t * th.x;
            accy += t * th.y;
        }
        float vx = ax + accx, vy = ay + accy;
        if (FINAL) {
            vx += bias[c]; vy += bias[c + 1];
            vx = LRELU(vx); vy = LRELU(vy);
        }
        float2 r; r.x = vx; r.y = vy;
        *(float2*)&w_new[(size_t)row * 120 + c] = r;
    }
}

// ============================ small CSR SpMMs ================================
// conv1 powers: thread per row, float4 channels. SP slot kout = L * slot kin
__global__ void k_csr_sp4(const int* __restrict__ rp, const int* __restrict__ col2,
                          const float* __restrict__ val2,
                          float* __restrict__ SP, int M, int kin, int kout) {
    int row = blockIdx.x * blockDim.x + threadIdx.x;
    if (row >= M) return;
    int e0 = rp[row], e1 = rp[row + 1];
    float ax = 0.f, ay = 0.f, az = 0.f, aw = 0.f;
    for (int e = e0; e < e1; ++e) {
        float v = val2[e];
        float4 xv = *(const float4*)&SP[(size_t)col2[e] * 20 + kin * 4];
        ax += v * xv.x; ay += v * xv.y; az += v * xv.z; aw += v * xv.w;
    }
    float4 r; r.x = ax; r.y = ay; r.z = az; r.w = aw;
    *(float4*)&SP[(size_t)row * 20 + kout * 4] = r;
}

// conv3 Horner: out(z_k) += L * in(z_{k+1}), thread per row, float4
__global__ void k_csr44(const int* __restrict__ rp, const int* __restrict__ col2,
                        const float* __restrict__ val2,
                        const float* __restrict__ in, float* __restrict__ out, int M) {
    int row = blockIdx.x * blockDim.x + threadIdx.x;
    if (row >= M) return;
    int e0 = rp[row], e1 = rp[row + 1];
    float4 acc = *(const float4*)&out[(size_t)row * 4];
    for (int e = e0; e < e1; ++e) {
        float v = val2[e];
        float4 xv = *(const float4*)&in[(size_t)col2[e] * 4];
        acc.x += v * xv.x; acc.y += v * xv.y; acc.z += v * xv.z; acc.w += v * xv.w;
    }
    *(float4*)&out[(size_t)row * 4] = acc;
}

// ============================ dense mixing ==================================
// conv1 GEMM: y[m,o] = lrelu(bias[o] + sum_kk th[kk][o]*SP[m,kk]), kk<20
__global__ __launch_bounds__(256) void k_gemm_c1(
    const float* __restrict__ SP, const float* __restrict__ tht, // (20,128)
    const float* __restrict__ bias, float* __restrict__ y) {
    __shared__ float in_lds[64 * 20];
    __shared__ float th_lds[20 * 128];
    int mb0 = blockIdx.x * 64;
    int tid = threadIdx.x;
    {
        const float4* s = (const float4*)tht;
        float4* d = (float4*)th_lds;
        for (int t = tid; t < 640; t += 256) d[t] = s[t];
    }
    {
        const float4* s = (const float4*)(SP + (size_t)mb0 * 20);
        float4* d = (float4*)in_lds;
        for (int t = tid; t < 320; t += 256) d[t] = s[t];
    }
    __syncthreads();
    int og = tid & 15, mbg = tid >> 4;
    int o = og * 8;
    float acc[4][8];
#pragma unroll
    for (int r = 0; r < 4; ++r)
#pragma unroll
        for (int c = 0; c < 8; ++c) acc[r][c] = 0.f;
#pragma unroll
    for (int kk = 0; kk < 20; ++kk) {
        float a0 = in_lds[(mbg * 4 + 0) * 20 + kk];
        float a1 = in_lds[(mbg * 4 + 1) * 20 + kk];
        float a2 = in_lds[(mbg * 4 + 2) * 20 + kk];
        float a3 = in_lds[(mbg * 4 + 3) * 20 + kk];
        float4 t0 = *(const float4*)&th_lds[kk * 128 + o];
        float4 t1 = *(const float4*)&th_lds[kk * 128 + o + 4];
        float tv[8] = {t0.x, t0.y, t0.z, t0.w, t1.x, t1.y, t1.z, t1.w};
#pragma unroll
        for (int c = 0; c < 8; ++c) {
            acc[0][c] += a0 * tv[c];
            acc[1][c] += a1 * tv[c];
            acc[2][c] += a2 * tv[c];
            acc[3][c] += a3 * tv[c];
        }
    }
    if (o < 120) {
#pragma unroll
        for (int r = 0; r < 4; ++r) {
            int mb = mb0 + mbg * 4 + r;
            float* yp = y + (size_t)mb * 120 + o;
#pragma unroll
            for (int c = 0; c < 8; ++c) {
                float v = acc[r][c] + bias[o + c];
                yp[c] = LRELU(v);
            }
        }
    }
}

// conv2 INIT GEMM: y = tht^T . tin (Cin=120 -> Cout=120), no bias/act
__global__ __launch_bounds__(256) void k_gemm120i(
    const float* __restrict__ tin,  // (Mp,120)
    const float* __restrict__ tht,  // (120,128) slice
    float* __restrict__ y) {        // (Mp,120)
    __shared__ float in_lds[64 * 124];
    __shared__ float th_lds[120 * 128];
    int mb0 = blockIdx.x * 64;
    int tid = threadIdx.x;
    {
        const float4* s = (const float4*)tht;
        float4* d = (float4*)th_lds;
#pragma unroll
        for (int t = 0; t < 15; ++t) d[tid + t * 256] = s[tid + t * 256];
    }
    {
        const float4* s = (const float4*)(tin + (size_t)mb0 * 120);
        for (int t = tid; t < 1920; t += 256) {
            int row = t / 30, q = t - row * 30;
            *(float4*)&in_lds[row * 124 + q * 4] = s[t];
        }
    }
    __syncthreads();
    int og = tid & 15, mbg = tid >> 4;
    int o = og * 8;
    float acc[4][8];
#pragma unroll
    for (int r = 0; r < 4; ++r)
#pragma unroll
        for (int c = 0; c < 8; ++c) acc[r][c] = 0.f;
#pragma unroll 4
    for (int i = 0; i < 120; ++i) {
        float a0 = in_lds[(mbg * 4 + 0) * 124 + i];
        float a1 = in_lds[(mbg * 4 + 1) * 124 + i];
        float a2 = in_lds[(mbg * 4 + 2) * 124 + i];
        float a3 = in_lds[(mbg * 4 + 3) * 124 + i];
        float4 t0 = *(const float4*)&th_lds[i * 128 + o];
        float4 t1 = *(const float4*)&th_lds[i * 128 + o + 4];
        float tv[8] = {t0.x, t0.y, t0.z, t0.w, t1.x, t1.y, t1.z, t1.w};
#pragma unroll
        for (int c = 0; c < 8; ++c) {
            acc[0][c] += a0 * tv[c];
            acc[1][c] += a1 * tv[c];
            acc[2][c] += a2 * tv[c];
            acc[3][c] += a3 * tv[c];
        }
    }
    if (o < 120) {
#pragma unroll
        for (int r = 0; r < 4; ++r) {
            int mb = mb0 + mbg * 4 + r;
            float* yp = y + (size_t)mb * 120 + o;
#pragma unroll
            for (int c = 0; c < 8; ++c) yp[c] = acc[r][c];
        }
    }
}

// conv3 z-pass: z_k[m,o] = sum_i th[k][i][o]*x[m,i]; z_0 += bias
__global__ __launch_bounds__(256) void k_zconv3(
    const float* __restrict__ x,   // (Mp,120)
    const float* __restrict__ tht, // (5*120*4) [k][i][o]
    const float* __restrict__ bias,// 4
    float* __restrict__ z, int Mp) {
    __shared__ float x_lds[64 * 124];
    __shared__ float th_lds[2400];
    int mb0 = blockIdx.x * 64;
    int tid = threadIdx.x;
    for (int t = tid; t < 600; t += 256) ((float4*)th_lds)[t] = ((const float4*)tht)[t];
    {
        const float4* s = (const float4*)(x + (size_t)mb0 * 120);
        for (int t = tid; t < 1920; t += 256) {
            int row = t / 30, q = t - row * 30;
            *(float4*)&x_lds[row * 124 + q * 4] = s[t];
        }
    }
    __syncthreads();
    int o = tid & 3, mbl = tid >> 2;
    float acc[5] = {0.f, 0.f, 0.f, 0.f, 0.f};
    for (int i = 0; i < 120; ++i) {
        float xv = x_lds[mbl * 124 + i];
#pragma unroll
        for (int k = 0; k < 5; ++k) acc[k] += xv * th_lds[(k * 120 + i) * 4 + o];
    }
    acc[0] += bias[o];
    int mb = mb0 + mbl;
    size_t slice = (size_t)Mp * 4;
#pragma unroll
    for (int k = 0; k < 5; ++k) z[k * slice + (size_t)mb * 4 + o] = acc[k];
}

// ---- final per-batch transpose: dout[o*M + m] = z0[m*4 + o] ----------------
__global__ void k_xpose_out(const float* __restrict__ z0, float* __restrict__ dout, int M) {
    int idx = blockIdx.x * blockDim.x + threadIdx.x;
    if (idx >= M * 4) return;
    int o = idx / M, m = idx - o * M;
    dout[idx] = z0[(size_t)m * 4 + o];
}

static inline int cdiv(long a, long b) { return (int)((a + b - 1) / b); }

extern "C" void kernel_launch(void* const* d_in, const int* in_sizes, int n_in,
                              void* d_out, int out_size, void* d_ws, size_t ws_size,
                              hipStream_t stream) {
    const int MSa[3]  = {40000, 100000, 60000};
    const int NNZa[3] = {400000, 1000000, 600000};
    const float* xs[3] = {(const float*)d_in[0], (const float*)d_in[4], (const float*)d_in[8]};
    const int* rr[3]   = {(const int*)d_in[1], (const int*)d_in[5], (const int*)d_in[9]};
    const int* cc[3]   = {(const int*)d_in[2], (const int*)d_in[6], (const int*)d_in[10]};
    const float* vv[3] = {(const float*)d_in[3], (const float*)d_in[7], (const float*)d_in[11]};

    float* out = (float*)d_out;
    size_t out_off = 0;

    for (int t = 0; t < 3; ++t) {
        const int M = MSa[t], nnz = NNZa[t];
        const int Mp = ((M + 63) / 64) * 64;
        const size_t slab = (size_t)Mp * 120;   // floats

        const float* th1 = (const float*)d_in[12 + t * 6 + 0];
        const float* b1  = (const float*)d_in[12 + t * 6 + 1];
        const float* th2 = (const float*)d_in[12 + t * 6 + 2];
        const float* b2  = (const float*)d_in[12 + t * 6 + 3];
        const float* th3 = (const float*)d_in[12 + t * 6 + 4];
        const float* b3  = (const float*)d_in[12 + t * 6 + 5];

        float* P0   = (float*)d_ws;
        float* P1   = P0 + slab;
        float* P2   = P1 + slab;            // aliases conv1 SP (Mp*20) & conv3 z (Mp*20)
        float* TH1  = P2 + slab;            // 2560 floats  (20,128)
        float* TH2  = TH1 + 2560;           // 76800 floats (5,120,128) - INIT k=4
        float* TH2B = TH2 + 76800;          // 72000 floats (5,120,120) - fused k=0..3
        float* TH3  = TH2B + 72000;         // 2400 floats  (5,120,4)
        int*   RP   = (int*)(TH3 + 2400);   // M+1
        int*   CUR  = RP + (Mp + 64);       // M (histogram + scatter cursor)
        int*   PART = CUR + Mp;             // <=512 block partials
        int*   COL2 = PART + 512;           // nnz
        float* VAL2 = (float*)(COL2 + nnz); // nnz

        // ---- theta repacks ----
        k_xpose_th<<<cdiv(2560, 256), 256, 0, stream>>>(th1, TH1, 120, 4, 5, 128);
        k_xpose_th<<<cdiv(76800, 256), 256, 0, stream>>>(th2, TH2, 120, 120, 5, 128);
        k_xpose_th<<<cdiv(72000, 256), 256, 0, stream>>>(th2, TH2B, 120, 120, 5, 120);
        k_xpose_th<<<cdiv(2400, 256), 256, 0, stream>>>(th3, TH3, 4, 120, 5, 4);

        // ---- CSR build (once per tower) ----
        const int nblkM = cdiv(M, 256);
        hipMemsetAsync(CUR, 0, (size_t)M * sizeof(int), stream);
        k_hist<<<cdiv(nnz, 256), 256, 0, stream>>>(rr[t], nnz, CUR);
        k_scan1<<<nblkM, 256, 0, stream>>>(CUR, M, RP, PART);
        k_scan2<<<1, 512, 0, stream>>>(PART, nblkM);
        k_scan3<<<nblkM, 256, 0, stream>>>(RP, CUR, PART, M, nnz);
        k_scatter<<<cdiv(nnz, 256), 256, 0, stream>>>(rr[t], cc[t], vv[t], nnz, CUR, COL2, VAL2);

        for (int b = 0; b < 2; ++b) {
            const float* xb = xs[t] + (size_t)b * 4 * M;
            float* outb = out + out_off + (size_t)b * 4 * M;

            // ---- conv1: powers of L (4ch) in P2 SP region, fused GEMM ----
            k_xpose_in<<<cdiv((long)M * 4, 256), 256, 0, stream>>>(xb, P2, M);
            for (int k = 1; k <= 4; ++k)
                k_csr_sp4<<<cdiv(M, 256), 256, 0, stream>>>(RP, COL2, VAL2, P2, M, k - 1, k);
            k_gemm_c1<<<Mp / 64, 256, 0, stream>>>(P2, TH1, b1, P0);

            // ---- conv2 (Horner, fused): w4=Th4 x; w=Th_k x + L w ----
            k_gemm120i<<<Mp / 64, 256, 0, stream>>>(P0, TH2 + (size_t)4 * 15360, P1);
            k_fused<0><<<cdiv(M, 16), 1024, 0, stream>>>(
                RP, COL2, VAL2, P1, P0, TH2B + (size_t)3 * 14400, nullptr, P2, M);
            k_fused<0><<<cdiv(M, 16), 1024, 0, stream>>>(
                RP, COL2, VAL2, P2, P0, TH2B + (size_t)2 * 14400, nullptr, P1, M);
            k_fused<0><<<cdiv(M, 16), 1024, 0, stream>>>(
                RP, COL2, VAL2, P1, P0, TH2B + (size_t)1 * 14400, nullptr, P2, M);
            k_fused<1><<<cdiv(M, 16), 1024, 0, stream>>>(
                RP, COL2, VAL2, P2, P0, TH2B, b2, P1, M);

            // ---- conv3: z_k = Theta_k out2 in P2, then in-place Horner ----
            k_zconv3<<<Mp / 64, 256, 0, stream>>>(P1, TH3, b3, P2, Mp);
            for (int k = 3; k >= 0; --k)
                k_csr44<<<cdiv(M, 256), 256, 0, stream>>>(
                    RP, COL2, VAL2,
                    P2 + (size_t)(k + 1) * Mp * 4, P2 + (size_t)k * Mp * 4, M);

            k_xpose_out<<<cdiv((long)M * 4, 256), 256, 0, stream>>>(P2, outb, M);
        }
        out_off += (size_t)M * 8;
    }
    (void)in_sizes; (void)n_in; (void)out_size; (void)ws_size;
}

// Round 11
// 4486.530 us; speedup vs baseline: 1.2167x; 1.2167x over previous
//
#include <hip/hip_runtime.h>
#include <hip/hip_bf16.h>
#include <hip/hip_fp16.h>

// ---------------------------------------------------------------------------
// MySCNN: 3 towers x (conv 4->120, conv 120->120, conv 120->4), K=5, lrelu.
// Round 7->8: REVERT k_fused (barrier coupled variable-length rows: -15%).
// Back to round-6 separated csr + accumulate-GEMM structure, with ONE change:
// conv2 ping-pong slabs stored fp16 (compute fp32) -> halves gather bytes.
//   H0/H1: (Mp,120) fp16 ping-pong. P1: (Mp,120) fp32 y accumulator.
//   SPZ (conv1 powers, conv3 z; fp32 Mp*20) aliases H1 (temporally dead).
// conv1: input-side powers (4ch fp32) -> gemm_c1 -> H0 fp16.
// conv2: y = sum_k Theta_k (L^k t): INIT gemm + 4x (csr120h; acc gemm).
// conv3: z_k = Theta_k out2 (fp32), output-side Horner z_k += L z_{k+1}.
// Pad rows [M,Mp) inert (may hold NaN; never read by valid rows).
// ---------------------------------------------------------------------------

#define LRELU(v) ((v) > 0.f ? (v) : 0.01f * (v))

// ---- per-batch transpose x (4,M) -> SP slot k=0: SP[m*20 + i] --------------
__global__ void k_xpose_in(const float* __restrict__ x, float* __restrict__ SP, int M) {
    int idx = blockIdx.x * blockDim.x + threadIdx.x;
    if (idx >= M * 4) return;
    int i = idx / M, m = idx - i * M;
    SP[(size_t)m * 20 + i] = x[idx];
}

// ---- theta transpose: dst[(k*Cin+i)*Cpad + o] = src[(o*Cin+i)*K + k] -------
__global__ void k_xpose_th(const float* __restrict__ src, float* __restrict__ dst,
                           int Cout, int Cin, int K, int Cpad) {
    int idx = blockIdx.x * blockDim.x + threadIdx.x;
    int tot = K * Cin * Cpad;
    if (idx >= tot) return;
    int o = idx % Cpad;
    int rest = idx / Cpad;
    int i = rest % Cin;
    int k = rest / Cin;
    dst[idx] = (o < Cout) ? src[((size_t)o * Cin + i) * K + k] : 0.f;
}

// ============================ CSR build =====================================
__global__ void k_hist(const int* __restrict__ rows, int nnz, int* __restrict__ cnt) {
    int e = blockIdx.x * blockDim.x + threadIdx.x;
    if (e < nnz) atomicAdd(&cnt[rows[e]], 1);
}

__global__ __launch_bounds__(256) void k_scan1(const int* __restrict__ cnt, int M,
                                               int* __restrict__ rp, int* __restrict__ part) {
    __shared__ int lds[256];
    int tid = threadIdx.x;
    int i = blockIdx.x * 256 + tid;
    int v = (i < M) ? cnt[i] : 0;
    lds[tid] = v;
    __syncthreads();
    for (int off = 1; off < 256; off <<= 1) {
        int t = (tid >= off) ? lds[tid - off] : 0;
        __syncthreads();
        lds[tid] += t;
        __syncthreads();
    }
    if (i < M) rp[i] = lds[tid] - v;
    if (tid == 255) part[blockIdx.x] = lds[255];
}

__global__ __launch_bounds__(512) void k_scan2(int* __restrict__ part, int npart) {
    __shared__ int lds[512];
    int tid = threadIdx.x;
    int v = (tid < npart) ? part[tid] : 0;
    lds[tid] = v;
    __syncthreads();
    for (int off = 1; off < 512; off <<= 1) {
        int t = (tid >= off) ? lds[tid - off] : 0;
        __syncthreads();
        lds[tid] += t;
        __syncthreads();
    }
    if (tid < npart) part[tid] = lds[tid] - v;
}

__global__ void k_scan3(int* __restrict__ rp, int* __restrict__ cur,
                        const int* __restrict__ part, int M, int nnz) {
    int i = blockIdx.x * 256 + threadIdx.x;
    if (i < M) {
        int r = rp[i] + part[blockIdx.x];
        rp[i] = r;
        cur[i] = r;
    }
    if (i == 0) rp[M] = nnz;
}

__global__ void k_scatter(const int* __restrict__ rows, const int* __restrict__ cols,
                          const float* __restrict__ vals, int nnz,
                          int* __restrict__ cur, int* __restrict__ col2,
                          float* __restrict__ val2) {
    int e = blockIdx.x * blockDim.x + threadIdx.x;
    if (e >= nnz) return;
    int pos = atomicAdd(&cur[rows[e]], 1);
    col2[pos] = cols[e];
    val2[pos] = vals[e];
}

// ============================ CSR SpMM ======================================
// conv2: one wave per row, 120 fp16 channels as half2 per lane (lanes 0..59)
__global__ __launch_bounds__(256) void k_csr120h(
    const int* __restrict__ rp, const int* __restrict__ col2,
    const float* __restrict__ val2,
    const __half* __restrict__ in, __half* __restrict__ out, int M) {
    int wid = (blockIdx.x * 256 + threadIdx.x) >> 6;   // row
    if (wid >= M) return;
    int lane = threadIdx.x & 63;
    int e0 = rp[wid], e1 = rp[wid + 1];
    int c = lane * 2;
    bool act = c < 120;
    float ax = 0.f, ay = 0.f;
    for (int e = e0; e < e1; ++e) {
        float v = val2[e];
        int col = col2[e];
        if (act) {
            __half2 h = *(const __half2*)&in[(size_t)col * 120 + c];
            float2 xf = __half22float2(h);
            ax += v * xf.x;
            ay += v * xf.y;
        }
    }
    if (act) *(__half2*)&out[(size_t)wid * 120 + c] = __floats2half2_rn(ax, ay);
}

// conv1 powers: thread per row, float4 channels. SP slot kout = L * slot kin
__global__ void k_csr_sp4(const int* __restrict__ rp, const int* __restrict__ col2,
                          const float* __restrict__ val2,
                          float* __restrict__ SP, int M, int kin, int kout) {
    int row = blockIdx.x * blockDim.x + threadIdx.x;
    if (row >= M) return;
    int e0 = rp[row], e1 = rp[row + 1];
    float ax = 0.f, ay = 0.f, az = 0.f, aw = 0.f;
    for (int e = e0; e < e1; ++e) {
        float v = val2[e];
        float4 xv = *(const float4*)&SP[(size_t)col2[e] * 20 + kin * 4];
        ax += v * xv.x; ay += v * xv.y; az += v * xv.z; aw += v * xv.w;
    }
    float4 r; r.x = ax; r.y = ay; r.z = az; r.w = aw;
    *(float4*)&SP[(size_t)row * 20 + kout * 4] = r;
}

// conv3 Horner: out(z_k) += L * in(z_{k+1}), thread per row, float4
__global__ void k_csr44(const int* __restrict__ rp, const int* __restrict__ col2,
                        const float* __restrict__ val2,
                        const float* __restrict__ in, float* __restrict__ out, int M) {
    int row = blockIdx.x * blockDim.x + threadIdx.x;
    if (row >= M) return;
    int e0 = rp[row], e1 = rp[row + 1];
    float4 acc = *(const float4*)&out[(size_t)row * 4];
    for (int e = e0; e < e1; ++e) {
        float v = val2[e];
        float4 xv = *(const float4*)&in[(size_t)col2[e] * 4];
        acc.x += v * xv.x; acc.y += v * xv.y; acc.z += v * xv.z; acc.w += v * xv.w;
    }
    *(float4*)&out[(size_t)row * 4] = acc;
}

// ============================ dense mixing ==================================
// conv1 GEMM: y[m,o] = lrelu(bias[o] + sum_kk th[kk][o]*SP[m,kk]) -> fp16
__global__ __launch_bounds__(256) void k_gemm_c1(
    const float* __restrict__ SP, const float* __restrict__ tht, // (20,128)
    const float* __restrict__ bias, __half* __restrict__ y) {
    __shared__ float in_lds[64 * 20];
    __shared__ float th_lds[20 * 128];
    int mb0 = blockIdx.x * 64;
    int tid = threadIdx.x;
    {
        const float4* s = (const float4*)tht;
        float4* d = (float4*)th_lds;
        for (int t = tid; t < 640; t += 256) d[t] = s[t];
    }
    {
        const float4* s = (const float4*)(SP + (size_t)mb0 * 20);
        float4* d = (float4*)in_lds;
        for (int t = tid; t < 320; t += 256) d[t] = s[t];
    }
    __syncthreads();
    int og = tid & 15, mbg = tid >> 4;
    int o = og * 8;
    float acc[4][8];
#pragma unroll
    for (int r = 0; r < 4; ++r)
#pragma unroll
        for (int c = 0; c < 8; ++c) acc[r][c] = 0.f;
#pragma unroll
    for (int kk = 0; kk < 20; ++kk) {
        float a0 = in_lds[(mbg * 4 + 0) * 20 + kk];
        float a1 = in_lds[(mbg * 4 + 1) * 20 + kk];
        float a2 = in_lds[(mbg * 4 + 2) * 20 + kk];
        float a3 = in_lds[(mbg * 4 + 3) * 20 + kk];
        float4 t0 = *(const float4*)&th_lds[kk * 128 + o];
        float4 t1 = *(const float4*)&th_lds[kk * 128 + o + 4];
        float tv[8] = {t0.x, t0.y, t0.z, t0.w, t1.x, t1.y, t1.z, t1.w};
#pragma unroll
        for (int c = 0; c < 8; ++c) {
            acc[0][c] += a0 * tv[c];
            acc[1][c] += a1 * tv[c];
            acc[2][c] += a2 * tv[c];
            acc[3][c] += a3 * tv[c];
        }
    }
    if (o < 120) {
#pragma unroll
        for (int r = 0; r < 4; ++r) {
            int mb = mb0 + mbg * 4 + r;
            __half* yp = y + (size_t)mb * 120 + o;
#pragma unroll
            for (int c = 0; c < 8; c += 2) {
                float va = acc[r][c] + bias[o + c];     va = LRELU(va);
                float vb = acc[r][c + 1] + bias[o + c + 1]; vb = LRELU(vb);
                *(__half2*)&yp[c] = __floats2half2_rn(va, vb);
            }
        }
    }
}

// conv2 GEMM: y (+)= tht_k^T . tin  (tin fp16, y fp32)
template <int INIT, int FINAL>
__global__ __launch_bounds__(256) void k_gemm120(
    const __half* __restrict__ tin, // (Mp,120) fp16
    const float* __restrict__ tht,  // (120,128) slice for this k
    const float* __restrict__ bias, // 120 (FINAL only)
    float* __restrict__ y) {        // (Mp,120) fp32
    __shared__ float in_lds[64 * 124];
    __shared__ float th_lds[120 * 128];
    int mb0 = blockIdx.x * 64;
    int tid = threadIdx.x;
    {
        const float4* s = (const float4*)tht;
        float4* d = (float4*)th_lds;
#pragma unroll
        for (int t = 0; t < 15; ++t) d[tid + t * 256] = s[tid + t * 256];
    }
    {
        // 64 rows x 120 fp16 = 960 chunks of 8 halves (16B)
        const float4* s = (const float4*)(tin + (size_t)mb0 * 120);
        for (int t = tid; t < 960; t += 256) {
            int row = t / 15, q = t - row * 15;
            float4 raw = s[t];
            const __half2* hp = (const __half2*)&raw;
            float* d = &in_lds[row * 124 + q * 8];
#pragma unroll
            for (int j = 0; j < 4; ++j) {
                float2 f = __half22float2(hp[j]);
                d[2 * j] = f.x;
                d[2 * j + 1] = f.y;
            }
        }
    }
    __syncthreads();
    int og = tid & 15, mbg = tid >> 4;
    int o = og * 8;
    float acc[4][8];
#pragma unroll
    for (int r = 0; r < 4; ++r)
#pragma unroll
        for (int c = 0; c < 8; ++c) acc[r][c] = 0.f;
#pragma unroll 4
    for (int i = 0; i < 120; ++i) {
        float a0 = in_lds[(mbg * 4 + 0) * 124 + i];
        float a1 = in_lds[(mbg * 4 + 1) * 124 + i];
        float a2 = in_lds[(mbg * 4 + 2) * 124 + i];
        float a3 = in_lds[(mbg * 4 + 3) * 124 + i];
        float4 t0 = *(const float4*)&th_lds[i * 128 + o];
        float4 t1 = *(const float4*)&th_lds[i * 128 + o + 4];
        float tv[8] = {t0.x, t0.y, t0.z, t0.w, t1.x, t1.y, t1.z, t1.w};
#pragma unroll
        for (int c = 0; c < 8; ++c) {
            acc[0][c] += a0 * tv[c];
            acc[1][c] += a1 * tv[c];
            acc[2][c] += a2 * tv[c];
            acc[3][c] += a3 * tv[c];
        }
    }
    if (o < 120) {
#pragma unroll
        for (int r = 0; r < 4; ++r) {
            int mb = mb0 + mbg * 4 + r;
            float* yp = y + (size_t)mb * 120 + o;
#pragma unroll
            for (int c = 0; c < 8; ++c) {
                float v = acc[r][c];
                if (!INIT) v += yp[c];
                if (FINAL) { v += bias[o + c]; v = LRELU(v); }
                yp[c] = v;
            }
        }
    }
}

// conv3 z-pass: z_k[m,o] = sum_i th[k][i][o]*x[m,i]; z_0 += bias
__global__ __launch_bounds__(256) void k_zconv3(
    const float* __restrict__ x,   // (Mp,120) fp32
    const float* __restrict__ tht, // (5*120*4) [k][i][o]
    const float* __restrict__ bias,// 4
    float* __restrict__ z, int Mp) {
    __shared__ float x_lds[64 * 124];
    __shared__ float th_lds[2400];
    int mb0 = blockIdx.x * 64;
    int tid = threadIdx.x;
    for (int t = tid; t < 600; t += 256) ((float4*)th_lds)[t] = ((const float4*)tht)[t];
    {
        const float4* s = (const float4*)(x + (size_t)mb0 * 120);
        for (int t = tid; t < 1920; t += 256) {
            int row = t / 30, q = t - row * 30;
            *(float4*)&x_lds[row * 124 + q * 4] = s[t];
        }
    }
    __syncthreads();
    int o = tid & 3, mbl = tid >> 2;
    float acc[5] = {0.f, 0.f, 0.f, 0.f, 0.f};
    for (int i = 0; i < 120; ++i) {
        float xv = x_lds[mbl * 124 + i];
#pragma unroll
        for (int k = 0; k < 5; ++k) acc[k] += xv * th_lds[(k * 120 + i) * 4 + o];
    }
    acc[0] += bias[o];
    int mb = mb0 + mbl;
    size_t slice = (size_t)Mp * 4;
#pragma unroll
    for (int k = 0; k < 5; ++k) z[k * slice + (size_t)mb * 4 + o] = acc[k];
}

// ---- final per-batch transpose: dout[o*M + m] = z0[m*4 + o] ----------------
__global__ void k_xpose_out(const float* __restrict__ z0, float* __restrict__ dout, int M) {
    int idx = blockIdx.x * blockDim.x + threadIdx.x;
    if (idx >= M * 4) return;
    int o = idx / M, m = idx - o * M;
    dout[idx] = z0[(size_t)m * 4 + o];
}

static inline int cdiv(long a, long b) { return (int)((a + b - 1) / b); }

extern "C" void kernel_launch(void* const* d_in, const int* in_sizes, int n_in,
                              void* d_out, int out_size, void* d_ws, size_t ws_size,
                              hipStream_t stream) {
    const int MSa[3]  = {40000, 100000, 60000};
    const int NNZa[3] = {400000, 1000000, 600000};
    const float* xs[3] = {(const float*)d_in[0], (const float*)d_in[4], (const float*)d_in[8]};
    const int* rr[3]   = {(const int*)d_in[1], (const int*)d_in[5], (const int*)d_in[9]};
    const int* cc[3]   = {(const int*)d_in[2], (const int*)d_in[6], (const int*)d_in[10]};
    const float* vv[3] = {(const float*)d_in[3], (const float*)d_in[7], (const float*)d_in[11]};

    float* out = (float*)d_out;
    size_t out_off = 0;

    for (int t = 0; t < 3; ++t) {
        const int M = MSa[t], nnz = NNZa[t];
        const int Mp = ((M + 63) / 64) * 64;
        const size_t slab = (size_t)Mp * 120;   // elements

        const float* th1 = (const float*)d_in[12 + t * 6 + 0];
        const float* b1  = (const float*)d_in[12 + t * 6 + 1];
        const float* th2 = (const float*)d_in[12 + t * 6 + 2];
        const float* b2  = (const float*)d_in[12 + t * 6 + 3];
        const float* th3 = (const float*)d_in[12 + t * 6 + 4];
        const float* b3  = (const float*)d_in[12 + t * 6 + 5];

        __half* H0  = (__half*)d_ws;            // (Mp,120) fp16 ping
        __half* H1  = H0 + slab;                // (Mp,120) fp16 pong
        float*  P1  = (float*)(H1 + slab);      // (Mp,120) fp32 y
        float*  TH1 = P1 + slab;                // 2560 floats  (20,128)
        float*  TH2 = TH1 + 2560;               // 76800 floats (5,120,128)
        float*  TH3 = TH2 + 76800;              // 2400 floats  (5,120,4)
        int*    RP   = (int*)(TH3 + 2400);      // M+1
        int*    CUR  = RP + (Mp + 64);          // M (histogram + scatter cursor)
        int*    PART = CUR + Mp;                // <=512 block partials
        int*    COL2 = PART + 512;              // nnz
        float*  VAL2 = (float*)(COL2 + nnz);    // nnz
        float*  SPZ  = (float*)H1;              // conv1 SP / conv3 z (Mp*20 fp32), aliases H1

        // ---- theta repacks ----
        k_xpose_th<<<cdiv(2560, 256), 256, 0, stream>>>(th1, TH1, 120, 4, 5, 128);
        k_xpose_th<<<cdiv(76800, 256), 256, 0, stream>>>(th2, TH2, 120, 120, 5, 128);
        k_xpose_th<<<cdiv(2400, 256), 256, 0, stream>>>(th3, TH3, 4, 120, 5, 4);

        // ---- CSR build (once per tower) ----
        const int nblkM = cdiv(M, 256);
        hipMemsetAsync(CUR, 0, (size_t)M * sizeof(int), stream);
        k_hist<<<cdiv(nnz, 256), 256, 0, stream>>>(rr[t], nnz, CUR);
        k_scan1<<<nblkM, 256, 0, stream>>>(CUR, M, RP, PART);
        k_scan2<<<1, 512, 0, stream>>>(PART, nblkM);
        k_scan3<<<nblkM, 256, 0, stream>>>(RP, CUR, PART, M, nnz);
        k_scatter<<<cdiv(nnz, 256), 256, 0, stream>>>(rr[t], cc[t], vv[t], nnz, CUR, COL2, VAL2);

        for (int b = 0; b < 2; ++b) {
            const float* xb = xs[t] + (size_t)b * 4 * M;
            float* outb = out + out_off + (size_t)b * 4 * M;

            // ---- conv1: powers of L (4ch fp32) in SPZ, fused GEMM -> H0 fp16
            k_xpose_in<<<cdiv((long)M * 4, 256), 256, 0, stream>>>(xb, SPZ, M);
            for (int k = 1; k <= 4; ++k)
                k_csr_sp4<<<cdiv(M, 256), 256, 0, stream>>>(RP, COL2, VAL2, SPZ, M, k - 1, k);
            k_gemm_c1<<<Mp / 64, 256, 0, stream>>>(SPZ, TH1, b1, H0);

            // ---- conv2: y = sum_k Theta_k (L^k t); fp16 ping-pong H0<->H1
            k_gemm120<1, 0><<<Mp / 64, 256, 0, stream>>>(H0, TH2, nullptr, P1);
            {
                __half* tsrc = H0;
                __half* tdst = H1;      // first csr write clobbers SPZ (dead)
                for (int k = 1; k <= 4; ++k) {
                    k_csr120h<<<cdiv(M, 4), 256, 0, stream>>>(
                        RP, COL2, VAL2, tsrc, tdst, M);
                    if (k < 4)
                        k_gemm120<0, 0><<<Mp / 64, 256, 0, stream>>>(
                            tdst, TH2 + (size_t)k * 15360, nullptr, P1);
                    else
                        k_gemm120<0, 1><<<Mp / 64, 256, 0, stream>>>(
                            tdst, TH2 + (size_t)4 * 15360, b2, P1);
                    __half* tmp = tsrc; tsrc = tdst; tdst = tmp;
                }
            }

            // ---- conv3: z_k = Theta_k out2 (SPZ, H1 dead again), Horner ----
            k_zconv3<<<Mp / 64, 256, 0, stream>>>(P1, TH3, b3, SPZ, Mp);
            for (int k = 3; k >= 0; --k)
                k_csr44<<<cdiv(M, 256), 256, 0, stream>>>(
                    RP, COL2, VAL2,
                    SPZ + (size_t)(k + 1) * Mp * 4, SPZ + (size_t)k * Mp * 4, M);

            k_xpose_out<<<cdiv((long)M * 4, 256), 256, 0, stream>>>(SPZ, outb, M);
        }
        out_off += (size_t)M * 8;
    }
    (void)in_sizes; (void)n_in; (void)out_size; (void)ws_size;
}

// Round 14
// 3365.954 us; speedup vs baseline: 1.6218x; 1.3329x over previous
//
#include <hip/hip_runtime.h>
#include <hip/hip_bf16.h>
#include <hip/hip_fp16.h>

// ---------------------------------------------------------------------------
// MySCNN: 3 towers x (conv 4->120, conv 120->120, conv 120->4), K=5, lrelu.
// Round 11->12 (two orthogonal changes, per-kernel attributable):
//  A) CSR kernels: edge loop unrolled x4 -> 4 independent gathers in flight
//     (r11 proved latency-bound: byte-halving left dur ~unchanged).
//  B) conv2 as SEPARATED Horner: w=Th4 x; {csr: H1->H2; gemm: w=Thk x + Lw}.
//     All-fp16 slabs; fp32 y accumulator (P1) eliminated. Same math
//     (Theta commutes with L); NO intra-block coupling (r7 lesson).
// Buffers: H0=x(conv1 out), H1=w ping, H2=Lw pong; SPZ (conv1 powers /
// conv3 z, fp32 Mp*20) aliases H2 (dead during conv1 & conv3).
// Pad rows [M,Mp) inert. Compute fp32 everywhere; storage fp16.
// ---------------------------------------------------------------------------

#define LRELU(v) ((v) > 0.f ? (v) : 0.01f * (v))

// ---- per-batch transpose x (4,M) -> SP slot k=0: SP[m*20 + i] --------------
__global__ void k_xpose_in(const float* __restrict__ x, float* __restrict__ SP, int M) {
    int idx = blockIdx.x * blockDim.x + threadIdx.x;
    if (idx >= M * 4) return;
    int i = idx / M, m = idx - i * M;
    SP[(size_t)m * 20 + i] = x[idx];
}

// ---- theta transpose: dst[(k*Cin+i)*Cpad + o] = src[(o*Cin+i)*K + k] -------
__global__ void k_xpose_th(const float* __restrict__ src, float* __restrict__ dst,
                           int Cout, int Cin, int K, int Cpad) {
    int idx = blockIdx.x * blockDim.x + threadIdx.x;
    int tot = K * Cin * Cpad;
    if (idx >= tot) return;
    int o = idx % Cpad;
    int rest = idx / Cpad;
    int i = rest % Cin;
    int k = rest / Cin;
    dst[idx] = (o < Cout) ? src[((size_t)o * Cin + i) * K + k] : 0.f;
}

// ============================ CSR build =====================================
__global__ void k_hist(const int* __restrict__ rows, int nnz, int* __restrict__ cnt) {
    int e = blockIdx.x * blockDim.x + threadIdx.x;
    if (e < nnz) atomicAdd(&cnt[rows[e]], 1);
}

__global__ __launch_bounds__(256) void k_scan1(const int* __restrict__ cnt, int M,
                                               int* __restrict__ rp, int* __restrict__ part) {
    __shared__ int lds[256];
    int tid = threadIdx.x;
    int i = blockIdx.x * 256 + tid;
    int v = (i < M) ? cnt[i] : 0;
    lds[tid] = v;
    __syncthreads();
    for (int off = 1; off < 256; off <<= 1) {
        int t = (tid >= off) ? lds[tid - off] : 0;
        __syncthreads();
        lds[tid] += t;
        __syncthreads();
    }
    if (i < M) rp[i] = lds[tid] - v;
    if (tid == 255) part[blockIdx.x] = lds[255];
}

__global__ __launch_bounds__(512) void k_scan2(int* __restrict__ part, int npart) {
    __shared__ int lds[512];
    int tid = threadIdx.x;
    int v = (tid < npart) ? part[tid] : 0;
    lds[tid] = v;
    __syncthreads();
    for (int off = 1; off < 512; off <<= 1) {
        int t = (tid >= off) ? lds[tid - off] : 0;
        __syncthreads();
        lds[tid] += t;
        __syncthreads();
    }
    if (tid < npart) part[tid] = lds[tid] - v;
}

__global__ void k_scan3(int* __restrict__ rp, int* __restrict__ cur,
                        const int* __restrict__ part, int M, int nnz) {
    int i = blockIdx.x * 256 + threadIdx.x;
    if (i < M) {
        int r = rp[i] + part[blockIdx.x];
        rp[i] = r;
        cur[i] = r;
    }
    if (i == 0) rp[M] = nnz;
}

__global__ void k_scatter(const int* __restrict__ rows, const int* __restrict__ cols,
                          const float* __restrict__ vals, int nnz,
                          int* __restrict__ cur, int* __restrict__ col2,
                          float* __restrict__ val2) {
    int e = blockIdx.x * blockDim.x + threadIdx.x;
    if (e >= nnz) return;
    int pos = atomicAdd(&cur[rows[e]], 1);
    col2[pos] = cols[e];
    val2[pos] = vals[e];
}

// ============================ CSR SpMM (x4 unrolled) ========================
// conv2: one wave per row, fp16 120ch as half2/lane; 4 gathers in flight
__global__ __launch_bounds__(256) void k_csr120h(
    const int* __restrict__ rp, const int* __restrict__ col2,
    const float* __restrict__ val2,
    const __half* __restrict__ in, __half* __restrict__ out, int M) {
    int wid = (blockIdx.x * 256 + threadIdx.x) >> 6;   // row
    if (wid >= M) return;
    int lane = threadIdx.x & 63;
    int e0 = rp[wid], e1 = rp[wid + 1];
    int c = lane * 2;
    bool act = c < 120;
    const __half* __restrict__ base = in + c;
    float ax = 0.f, ay = 0.f;
    int e = e0;
    for (; e + 4 <= e1; e += 4) {
        int c0 = col2[e], c1 = col2[e + 1], c2 = col2[e + 2], c3 = col2[e + 3];
        float v0 = val2[e], v1 = val2[e + 1], v2 = val2[e + 2], v3 = val2[e + 3];
        if (act) {
            float2 f0 = __half22float2(*(const __half2*)&base[(size_t)c0 * 120]);
            float2 f1 = __half22float2(*(const __half2*)&base[(size_t)c1 * 120]);
            float2 f2 = __half22float2(*(const __half2*)&base[(size_t)c2 * 120]);
            float2 f3 = __half22float2(*(const __half2*)&base[(size_t)c3 * 120]);
            ax += v0 * f0.x; ay += v0 * f0.y;
            ax += v1 * f1.x; ay += v1 * f1.y;
            ax += v2 * f2.x; ay += v2 * f2.y;
            ax += v3 * f3.x; ay += v3 * f3.y;
        }
    }
    for (; e < e1; ++e) {
        float v = val2[e];
        int col = col2[e];
        if (act) {
            float2 f = __half22float2(*(const __half2*)&base[(size_t)col * 120]);
            ax += v * f.x; ay += v * f.y;
        }
    }
    if (act) *(__half2*)&out[(size_t)wid * 120 + c] = __floats2half2_rn(ax, ay);
}

// conv1 powers: thread per row, float4 channels, x4 unrolled
__global__ void k_csr_sp4(const int* __restrict__ rp, const int* __restrict__ col2,
                          const float* __restrict__ val2,
                          float* __restrict__ SP, int M, int kin, int kout) {
    int row = blockIdx.x * blockDim.x + threadIdx.x;
    if (row >= M) return;
    int e0 = rp[row], e1 = rp[row + 1];
    float ax = 0.f, ay = 0.f, az = 0.f, aw = 0.f;
    const float* __restrict__ base = SP + kin * 4;
    int e = e0;
    for (; e + 4 <= e1; e += 4) {
        int c0 = col2[e], c1 = col2[e + 1], c2 = col2[e + 2], c3 = col2[e + 3];
        float v0 = val2[e], v1 = val2[e + 1], v2 = val2[e + 2], v3 = val2[e + 3];
        float4 x0 = *(const float4*)&base[(size_t)c0 * 20];
        float4 x1 = *(const float4*)&base[(size_t)c1 * 20];
        float4 x2 = *(const float4*)&base[(size_t)c2 * 20];
        float4 x3 = *(const float4*)&base[(size_t)c3 * 20];
        ax += v0 * x0.x; ay += v0 * x0.y; az += v0 * x0.z; aw += v0 * x0.w;
        ax += v1 * x1.x; ay += v1 * x1.y; az += v1 * x1.z; aw += v1 * x1.w;
        ax += v2 * x2.x; ay += v2 * x2.y; az += v2 * x2.z; aw += v2 * x2.w;
        ax += v3 * x3.x; ay += v3 * x3.y; az += v3 * x3.z; aw += v3 * x3.w;
    }
    for (; e < e1; ++e) {
        float v = val2[e];
        float4 xv = *(const float4*)&base[(size_t)col2[e] * 20];
        ax += v * xv.x; ay += v * xv.y; az += v * xv.z; aw += v * xv.w;
    }
    float4 r; r.x = ax; r.y = ay; r.z = az; r.w = aw;
    *(float4*)&SP[(size_t)row * 20 + kout * 4] = r;
}

// conv3 Horner: out(z_k) += L * in(z_{k+1}), thread per row, x4 unrolled
__global__ void k_csr44(const int* __restrict__ rp, const int* __restrict__ col2,
                        const float* __restrict__ val2,
                        const float* __restrict__ in, float* __restrict__ out, int M) {
    int row = blockIdx.x * blockDim.x + threadIdx.x;
    if (row >= M) return;
    int e0 = rp[row], e1 = rp[row + 1];
    float4 acc = *(const float4*)&out[(size_t)row * 4];
    int e = e0;
    for (; e + 4 <= e1; e += 4) {
        int c0 = col2[e], c1 = col2[e + 1], c2 = col2[e + 2], c3 = col2[e + 3];
        float v0 = val2[e], v1 = val2[e + 1], v2 = val2[e + 2], v3 = val2[e + 3];
        float4 x0 = *(const float4*)&in[(size_t)c0 * 4];
        float4 x1 = *(const float4*)&in[(size_t)c1 * 4];
        float4 x2 = *(const float4*)&in[(size_t)c2 * 4];
        float4 x3 = *(const float4*)&in[(size_t)c3 * 4];
        acc.x += v0 * x0.x; acc.y += v0 * x0.y; acc.z += v0 * x0.z; acc.w += v0 * x0.w;
        acc.x += v1 * x1.x; acc.y += v1 * x1.y; acc.z += v1 * x1.z; acc.w += v1 * x1.w;
        acc.x += v2 * x2.x; acc.y += v2 * x2.y; acc.z += v2 * x2.z; acc.w += v2 * x2.w;
        acc.x += v3 * x3.x; acc.y += v3 * x3.y; acc.z += v3 * x3.z; acc.w += v3 * x3.w;
    }
    for (; e < e1; ++e) {
        float v = val2[e];
        float4 xv = *(const float4*)&in[(size_t)col2[e] * 4];
        acc.x += v * xv.x; acc.y += v * xv.y; acc.z += v * xv.z; acc.w += v * xv.w;
    }
    *(float4*)&out[(size_t)row * 4] = acc;
}

// ============================ dense mixing ==================================
// conv1 GEMM: y[m,o] = lrelu(bias[o] + sum_kk th[kk][o]*SP[m,kk]) -> fp16
__global__ __launch_bounds__(256) void k_gemm_c1(
    const float* __restrict__ SP, const float* __restrict__ tht, // (20,128)
    const float* __restrict__ bias, __half* __restrict__ y) {
    __shared__ float in_lds[64 * 20];
    __shared__ float th_lds[20 * 128];
    int mb0 = blockIdx.x * 64;
    int tid = threadIdx.x;
    {
        const float4* s = (const float4*)tht;
        float4* d = (float4*)th_lds;
        for (int t = tid; t < 640; t += 256) d[t] = s[t];
    }
    {
        const float4* s = (const float4*)(SP + (size_t)mb0 * 20);
        float4* d = (float4*)in_lds;
        for (int t = tid; t < 320; t += 256) d[t] = s[t];
    }
    __syncthreads();
    int og = tid & 15, mbg = tid >> 4;
    int o = og * 8;
    float acc[4][8];
#pragma unroll
    for (int r = 0; r < 4; ++r)
#pragma unroll
        for (int c = 0; c < 8; ++c) acc[r][c] = 0.f;
#pragma unroll
    for (int kk = 0; kk < 20; ++kk) {
        float a0 = in_lds[(mbg * 4 + 0) * 20 + kk];
        float a1 = in_lds[(mbg * 4 + 1) * 20 + kk];
        float a2 = in_lds[(mbg * 4 + 2) * 20 + kk];
        float a3 = in_lds[(mbg * 4 + 3) * 20 + kk];
        float4 t0 = *(const float4*)&th_lds[kk * 128 + o];
        float4 t1 = *(const float4*)&th_lds[kk * 128 + o + 4];
        float tv[8] = {t0.x, t0.y, t0.z, t0.w, t1.x, t1.y, t1.z, t1.w};
#pragma unroll
        for (int c = 0; c < 8; ++c) {
            acc[0][c] += a0 * tv[c];
            acc[1][c] += a1 * tv[c];
            acc[2][c] += a2 * tv[c];
            acc[3][c] += a3 * tv[c];
        }
    }
    if (o < 120) {
#pragma unroll
        for (int r = 0; r < 4; ++r) {
            int mb = mb0 + mbg * 4 + r;
            __half* yp = y + (size_t)mb * 120 + o;
#pragma unroll
            for (int c = 0; c < 8; c += 2) {
                float va = acc[r][c] + bias[o + c];     va = LRELU(va);
                float vb = acc[r][c + 1] + bias[o + c + 1]; vb = LRELU(vb);
                *(__half2*)&yp[c] = __floats2half2_rn(va, vb);
            }
        }
    }
}

// conv2 Horner GEMM: w[m,o] = (FINAL? lrelu(+bias):.)(Thk x[m] + (ADD? T[m,o]:0))
template <int ADD, int FINAL>
__global__ __launch_bounds__(256) void k_gemm120h(
    const __half* __restrict__ x,   // (Mp,120) fp16 GEMM operand
    const __half* __restrict__ T,   // (Mp,120) fp16 addend (L w), ADD only
    const float* __restrict__ tht,  // (120,128) slice [i][o]
    const float* __restrict__ bias, // 120 (FINAL only)
    __half* __restrict__ w) {       // (Mp,120) fp16
    __shared__ float in_lds[64 * 124];
    __shared__ float th_lds[120 * 128];
    int mb0 = blockIdx.x * 64;
    int tid = threadIdx.x;
    {
        const float4* s = (const float4*)tht;
        float4* d = (float4*)th_lds;
#pragma unroll
        for (int t = 0; t < 15; ++t) d[tid + t * 256] = s[tid + t * 256];
    }
    {
        // 64 rows x 120 fp16 = 960 chunks of 8 halves (16B)
        const float4* s = (const float4*)(x + (size_t)mb0 * 120);
        for (int t = tid; t < 960; t += 256) {
            int row = t / 15, q = t - row * 15;
            float4 raw = s[t];
            const __half2* hp = (const __half2*)&raw;
            float* d = &in_lds[row * 124 + q * 8];
#pragma unroll
            for (int j = 0; j < 4; ++j) {
                float2 f = __half22float2(hp[j]);
                d[2 * j] = f.x;
                d[2 * j + 1] = f.y;
            }
        }
    }
    __syncthreads();
    int og = tid & 15, mbg = tid >> 4;
    int o = og * 8;
    float acc[4][8];
#pragma unroll
    for (int r = 0; r < 4; ++r)
#pragma unroll
        for (int c = 0; c < 8; ++c) acc[r][c] = 0.f;
#pragma unroll 4
    for (int i = 0; i < 120; ++i) {
        float a0 = in_lds[(mbg * 4 + 0) * 124 + i];
        float a1 = in_lds[(mbg * 4 + 1) * 124 + i];
        float a2 = in_lds[(mbg * 4 + 2) * 124 + i];
        float a3 = in_lds[(mbg * 4 + 3) * 124 + i];
        float4 t0 = *(const float4*)&th_lds[i * 128 + o];
        float4 t1 = *(const float4*)&th_lds[i * 128 + o + 4];
        float tv[8] = {t0.x, t0.y, t0.z, t0.w, t1.x, t1.y, t1.z, t1.w};
#pragma unroll
        for (int c = 0; c < 8; ++c) {
            acc[0][c] += a0 * tv[c];
            acc[1][c] += a1 * tv[c];
            acc[2][c] += a2 * tv[c];
            acc[3][c] += a3 * tv[c];
        }
    }
    if (o < 120) {
#pragma unroll
        for (int r = 0; r < 4; ++r) {
            int mb = mb0 + mbg * 4 + r;
            __half* wp = w + (size_t)mb * 120 + o;
            float add[8];
            if (ADD) {
                float4 raw = *(const float4*)(T + (size_t)mb * 120 + o);
                const __half2* hp = (const __half2*)&raw;
#pragma unroll
                for (int j = 0; j < 4; ++j) {
                    float2 f = __half22float2(hp[j]);
                    add[2 * j] = f.x;
                    add[2 * j + 1] = f.y;
                }
            }
#pragma unroll
            for (int c = 0; c < 8; c += 2) {
                float va = acc[r][c];
                float vb = acc[r][c + 1];
                if (ADD) { va += add[c]; vb += add[c + 1]; }
                if (FINAL) {
                    va += bias[o + c];     va = LRELU(va);
                    vb += bias[o + c + 1]; vb = LRELU(vb);
                }
                *(__half2*)&wp[c] = __floats2half2_rn(va, vb);
            }
        }
    }
}

// conv3 z-pass: z_k[m,o] = sum_i th[k][i][o]*x[m,i]; z_0 += bias (x fp16)
__global__ __launch_bounds__(256) void k_zconv3(
    const __half* __restrict__ x,  // (Mp,120) fp16
    const float* __restrict__ tht, // (5*120*4) [k][i][o]
    const float* __restrict__ bias,// 4
    float* __restrict__ z, int Mp) {
    __shared__ float x_lds[64 * 124];
    __shared__ float th_lds[2400];
    int mb0 = blockIdx.x * 64;
    int tid = threadIdx.x;
    for (int t = tid; t < 600; t += 256) ((float4*)th_lds)[t] = ((const float4*)tht)[t];
    {
        const float4* s = (const float4*)(x + (size_t)mb0 * 120);
        for (int t = tid; t < 960; t += 256) {
            int row = t / 15, q = t - row * 15;
            float4 raw = s[t];
            const __half2* hp = (const __half2*)&raw;
            float* d = &x_lds[row * 124 + q * 8];
#pragma unroll
            for (int j = 0; j < 4; ++j) {
                float2 f = __half22float2(hp[j]);
                d[2 * j] = f.x;
                d[2 * j + 1] = f.y;
            }
        }
    }
    __syncthreads();
    int o = tid & 3, mbl = tid >> 2;
    float acc[5] = {0.f, 0.f, 0.f, 0.f, 0.f};
    for (int i = 0; i < 120; ++i) {
        float xv = x_lds[mbl * 124 + i];
#pragma unroll
        for (int k = 0; k < 5; ++k) acc[k] += xv * th_lds[(k * 120 + i) * 4 + o];
    }
    acc[0] += bias[o];
    int mb = mb0 + mbl;
    size_t slice = (size_t)Mp * 4;
#pragma unroll
    for (int k = 0; k < 5; ++k) z[k * slice + (size_t)mb * 4 + o] = acc[k];
}

// ---- final per-batch transpose: dout[o*M + m] = z0[m*4 + o] ----------------
__global__ void k_xpose_out(const float* __restrict__ z0, float* __restrict__ dout, int M) {
    int idx = blockIdx.x * blockDim.x + threadIdx.x;
    if (idx >= M * 4) return;
    int o = idx / M, m = idx - o * M;
    dout[idx] = z0[(size_t)m * 4 + o];
}

static inline int cdiv(long a, long b) { return (int)((a + b - 1) / b); }

extern "C" void kernel_launch(void* const* d_in, const int* in_sizes, int n_in,
                              void* d_out, int out_size, void* d_ws, size_t ws_size,
                              hipStream_t stream) {
    const int MSa[3]  = {40000, 100000, 60000};
    const int NNZa[3] = {400000, 1000000, 600000};
    const float* xs[3] = {(const float*)d_in[0], (const float*)d_in[4], (const float*)d_in[8]};
    const int* rr[3]   = {(const int*)d_in[1], (const int*)d_in[5], (const int*)d_in[9]};
    const int* cc[3]   = {(const int*)d_in[2], (const int*)d_in[6], (const int*)d_in[10]};
    const float* vv[3] = {(const float*)d_in[3], (const float*)d_in[7], (const float*)d_in[11]};

    float* out = (float*)d_out;
    size_t out_off = 0;

    for (int t = 0; t < 3; ++t) {
        const int M = MSa[t], nnz = NNZa[t];
        const int Mp = ((M + 63) / 64) * 64;
        const size_t slab = (size_t)Mp * 120;   // elements

        const float* th1 = (const float*)d_in[12 + t * 6 + 0];
        const float* b1  = (const float*)d_in[12 + t * 6 + 1];
        const float* th2 = (const float*)d_in[12 + t * 6 + 2];
        const float* b2  = (const float*)d_in[12 + t * 6 + 3];
        const float* th3 = (const float*)d_in[12 + t * 6 + 4];
        const float* b3  = (const float*)d_in[12 + t * 6 + 5];

        __half* H0  = (__half*)d_ws;            // x (conv1 out), fp16
        __half* H1  = H0 + slab;                // w ping, fp16
        __half* H2  = H1 + slab;                // Lw pong, fp16
        float*  TH1 = (float*)(H2 + slab);      // 2560 floats  (20,128)
        float*  TH2 = TH1 + 2560;               // 76800 floats (5,120,128)
        float*  TH3 = TH2 + 76800;              // 2400 floats  (5,120,4)
        int*    RP   = (int*)(TH3 + 2400);      // M+1
        int*    CUR  = RP + (Mp + 64);          // M (histogram + scatter cursor)
        int*    PART = CUR + Mp;                // <=512 block partials
        int*    COL2 = PART + 512;              // nnz
        float*  VAL2 = (float*)(COL2 + nnz);    // nnz
        float*  SPZ  = (float*)H2;              // conv1 SP / conv3 z (Mp*20 fp32)

        // ---- theta repacks ----
        k_xpose_th<<<cdiv(2560, 256), 256, 0, stream>>>(th1, TH1, 120, 4, 5, 128);
        k_xpose_th<<<cdiv(76800, 256), 256, 0, stream>>>(th2, TH2, 120, 120, 5, 128);
        k_xpose_th<<<cdiv(2400, 256), 256, 0, stream>>>(th3, TH3, 4, 120, 5, 4);

        // ---- CSR build (once per tower) ----
        const int nblkM = cdiv(M, 256);
        hipMemsetAsync(CUR, 0, (size_t)M * sizeof(int), stream);
        k_hist<<<cdiv(nnz, 256), 256, 0, stream>>>(rr[t], nnz, CUR);
        k_scan1<<<nblkM, 256, 0, stream>>>(CUR, M, RP, PART);
        k_scan2<<<1, 512, 0, stream>>>(PART, nblkM);
        k_scan3<<<nblkM, 256, 0, stream>>>(RP, CUR, PART, M, nnz);
        k_scatter<<<cdiv(nnz, 256), 256, 0, stream>>>(rr[t], cc[t], vv[t], nnz, CUR, COL2, VAL2);

        for (int b = 0; b < 2; ++b) {
            const float* xb = xs[t] + (size_t)b * 4 * M;
            float* outb = out + out_off + (size_t)b * 4 * M;

            // ---- conv1: powers of L (4ch fp32) in SPZ (=H2), GEMM -> H0 fp16
            k_xpose_in<<<cdiv((long)M * 4, 256), 256, 0, stream>>>(xb, SPZ, M);
            for (int k = 1; k <= 4; ++k)
                k_csr_sp4<<<cdiv(M, 256), 256, 0, stream>>>(RP, COL2, VAL2, SPZ, M, k - 1, k);
            k_gemm_c1<<<Mp / 64, 256, 0, stream>>>(SPZ, TH1, b1, H0);

            // ---- conv2 Horner: w=Th4 x; {csr H1->H2; w=Thk x + Lw} ----
            k_gemm120h<0, 0><<<Mp / 64, 256, 0, stream>>>(
                H0, nullptr, TH2 + (size_t)4 * 15360, nullptr, H1);
            for (int k = 3; k >= 1; --k) {
                k_csr120h<<<cdiv(M, 4), 256, 0, stream>>>(RP, COL2, VAL2, H1, H2, M);
                k_gemm120h<1, 0><<<Mp / 64, 256, 0, stream>>>(
                    H0, H2, TH2 + (size_t)k * 15360, nullptr, H1);
            }
            k_csr120h<<<cdiv(M, 4), 256, 0, stream>>>(RP, COL2, VAL2, H1, H2, M);
            k_gemm120h<1, 1><<<Mp / 64, 256, 0, stream>>>(H0, H2, TH2, b2, H1);

            // ---- conv3: z_k = Theta_k w0 into SPZ (=H2, dead), Horner ----
            k_zconv3<<<Mp / 64, 256, 0, stream>>>(H1, TH3, b3, SPZ, Mp);
            for (int k = 3; k >= 0; --k)
                k_csr44<<<cdiv(M, 256), 256, 0, stream>>>(
                    RP, COL2, VAL2,
                    SPZ + (size_t)(k + 1) * Mp * 4, SPZ + (size_t)k * Mp * 4, M);

            k_xpose_out<<<cdiv((long)M * 4, 256), 256, 0, stream>>>(SPZ, outb, M);
        }
        out_off += (size_t)M * 8;
    }
    (void)in_sizes; (void)n_in; (void)out_size; (void)ws_size;
}